// Round 13
// baseline (1761.941 us; speedup 1.0000x reference)
//
#include <hip/hip_runtime.h>

typedef float f32x4 __attribute__((ext_vector_type(4)));
typedef _Float16 f16;
typedef _Float16 f16x8 __attribute__((ext_vector_type(8)));
typedef unsigned int u32;
typedef unsigned short u16;

__device__ __forceinline__ u16 f2h(float f){
  f16 h = (f16)f; return __builtin_bit_cast(u16, h);
}
__device__ __forceinline__ float h2f(u16 u){
  f16 h = __builtin_bit_cast(f16, u); return (float)h;
}
__device__ __forceinline__ f16x8 ld16(const void* p){
  uint4 v = *(const uint4*)p;
  return __builtin_bit_cast(f16x8, v);
}
__device__ __forceinline__ f32x4 mm(f16x8 a, f16x8 b, f32x4 c){
  return __builtin_amdgcn_mfma_f32_16x16x32_f16(a, b, c, 0, 0, 0);
}

// ---------------- K0a: weights -> fp16, MFMA-fragment-major layout ----------------
// Fragment = 16 out-cols x 32 k; storage frag*512 + lane*8, elem j = W[col0+l15][k0+g*8+j].
__global__ void k_wconv(const float* __restrict__ qkvw, const float* __restrict__ projw,
                        const float* __restrict__ fc1w, const float* __restrict__ fc2w,
                        u16* __restrict__ o_qkv, u16* __restrict__ o_proj,
                        u16* __restrict__ o_fc1, u16* __restrict__ o_fc2){
  int t = blockIdx.x*256 + threadIdx.x;      // 1536 frags * 64 lanes = 98304
  int frag = t >> 6, lane = t & 63;
  int l15 = lane & 15, g = lane >> 4;
  const float* src; u16* dst; int col, k, ld, f;
  if(frag < 384){                             // qkv: frag = part*128 + h*16 + tc*8 + kk
    f = frag;
    int part = f >> 7, rem = f & 127;
    int h = rem >> 4, rem2 = rem & 15;
    int tc = rem2 >> 3, kk = rem2 & 7;
    col = part*256 + h*32 + tc*16 + l15; k = kk*32 + g*8;
    src = qkvw; dst = o_qkv; ld = 256;
  } else if(frag < 512){                      // proj: frag = w8*16 + tn2*8 + kk
    f = frag - 384;
    int w8 = f >> 4, rem = f & 15;
    int tn2 = rem >> 3, kk = rem & 7;
    col = w8*32 + tn2*16 + l15; k = kk*32 + g*8;
    src = projw; dst = o_proj; ld = 256;
  } else if(frag < 1024){                     // fc1: frag = ck*64 + wn8*8 + kk (128-col chunks)
    f = frag - 512;
    int ck = f >> 6, rem = f & 63;
    int wn8 = rem >> 3, kk = rem & 7;
    col = ck*128 + wn8*16 + l15; k = kk*32 + g*8;
    src = fc1w; dst = o_fc1; ld = 256;
  } else {                                    // fc2: frag = wn*128 + tn*32 + ck*4 + kk2 (128-k chunks)
    f = frag - 1024;
    int wn = f >> 7, rem = f & 127;
    int tn = rem >> 5, rem2 = rem & 31;
    int ck = rem2 >> 2, kk2 = rem2 & 3;
    col = wn*64 + tn*16 + l15; k = ck*128 + kk2*32 + g*8;
    src = fc2w; dst = o_fc2; ld = 1024;
  }
  float4 a = *(const float4*)(src + (size_t)col*ld + k);
  float4 b4 = *(const float4*)(src + (size_t)col*ld + k + 4);
  ushort4 h0, h1;
  h0.x=f2h(a.x); h0.y=f2h(a.y); h0.z=f2h(a.z); h0.w=f2h(a.w);
  h1.x=f2h(b4.x); h1.y=f2h(b4.y); h1.z=f2h(b4.z); h1.w=f2h(b4.w);
  u16* o = dst + (size_t)f*512 + lane*8;
  *(ushort4*)o = h0;
  *(ushort4*)(o+4) = h1;
}

// ---------------- K0b: CRPB bias table (8,64,64) ----------------
__global__ void k_bias(const float* __restrict__ w1, const float* __restrict__ b1,
                       const float* __restrict__ w2, float* __restrict__ bias){
  __shared__ float tab[225][8];
  int t = threadIdx.x;
  if(t < 225){
    int i15 = t/15, j15 = t%15;
    float di = (float)(i15-7) * (8.f/7.f);
    float dj = (float)(j15-7) * (8.f/7.f);
    float vi = copysignf(log2f(fabsf(di)+1.f)*(1.f/3.f), di);
    float vj = copysignf(log2f(fabsf(dj)+1.f)*(1.f/3.f), dj);
    float acc[8];
    #pragma unroll
    for(int h=0;h<8;h++) acc[h]=0.f;
    for(int c=0;c<384;c++){
      float hv = vi*w1[c*2] + vj*w1[c*2+1] + b1[c];
      hv = fmaxf(hv, 0.f);
      #pragma unroll
      for(int h=0;h<8;h++) acc[h] += hv * w2[h*384+c];
    }
    #pragma unroll
    for(int h=0;h<8;h++) tab[t][h] = acc[h];
  }
  __syncthreads();
  for(int pr = t; pr < 4096; pr += 256){
    int i = pr>>6, j = pr&63;
    int dh = (i>>3)-(j>>3)+7, dw = (i&7)-(j&7)+7;
    int idx = dh*15+dw;
    #pragma unroll
    for(int h=0;h<8;h++){
      float v = tab[idx][h];
      bias[(h*64+i)*64+j] = 16.f / (1.f + __expf(-v));
    }
  }
}

// ---------------- K1: fused shifted-window attention + LN1 ----------------
// R6 structure; QKV merged into ONE kk loop (acc[3][2][4]) -> 3x fewer A-frag
// LDS reads (96->32 ld16/wave) and less address VALU.
__global__ __launch_bounds__(512, 1)
void k_attn(const float* __restrict__ x, const u16* __restrict__ qkvw,
            const float* __restrict__ qkvb, const u16* __restrict__ projw,
            const float* __restrict__ projb, const float* __restrict__ tsc,
            const float* __restrict__ biastab,
            const float* __restrict__ n1w, const float* __restrict__ n1b,
            u16* __restrict__ y)
{
  extern __shared__ char sm[];
  const int tid = threadIdx.x;
  const int w = tid >> 6, lane = tid & 63;
  const int l15 = lane & 15, g = lane >> 4;
  const int blk = blockIdx.x;
  const int b = blk >> 6, nw = blk & 63, wh = nw >> 3, wwi = nw & 7;

  char* Wq = sm + 32768 + w*12288;
  char* Wk = Wq + 4096;
  char* Wv = Wq + 8192;
  char* Wp = Wq;  // aliases q+k after S fragments are in registers
  float* nrmq = (float*)(sm + 131072 + w*512);
  float* nrmk = nrmq + 64;

  // ---- stage shifted x window -> fp16 LDS ----
  {
    int row = tid >> 3, seg = tid & 7;
    int hs = ((wh<<3) + (row>>3) + 4) & 63;
    int ws_ = ((wwi<<3) + (row&7) + 4) & 63;
    const float* src = x + (size_t)(b*4096 + hs*64 + ws_)*256 + seg*32;
    char* drow = sm + row*512;
    int sw = (row & 7) << 4;
    #pragma unroll
    for(int u=0; u<4; u++){
      float4 f0 = ((const float4*)src)[2*u];
      float4 f1 = ((const float4*)src)[2*u+1];
      uint4 pk;
      pk.x = (u32)f2h(f0.x) | ((u32)f2h(f0.y)<<16);
      pk.y = (u32)f2h(f0.z) | ((u32)f2h(f0.w)<<16);
      pk.z = (u32)f2h(f1.x) | ((u32)f2h(f1.y)<<16);
      pk.w = (u32)f2h(f1.z) | ((u32)f2h(f1.w)<<16);
      *(uint4*)(drow + (((seg<<6) + (u<<4)) ^ sw)) = pk;
    }
  }
  __syncthreads();

  const int h = w;  // one head per wave
  // ---- QKV GEMM, single kk loop over all 3 parts ----
  {
    f32x4 acc[3][2][4] = {};
    #pragma unroll
    for(int kk=0; kk<8; kk++){
      f16x8 a[4];
      #pragma unroll
      for(int tm=0; tm<4; tm++){
        int row = tm*16 + l15;
        a[tm] = ld16(sm + row*512 + (((kk<<6) + (g<<4)) ^ ((row&7)<<4)));
      }
      #pragma unroll
      for(int part=0; part<3; part++){
        #pragma unroll
        for(int tc=0; tc<2; tc++){
          f16x8 bf = ld16(qkvw + (size_t)(part*128 + h*16 + tc*8 + kk)*512 + lane*8);
          #pragma unroll
          for(int tm=0; tm<4; tm++) acc[part][tc][tm] = mm(a[tm], bf, acc[part][tc][tm]);
        }
      }
    }
    #pragma unroll
    for(int part=0; part<3; part++){
      #pragma unroll
      for(int tc=0; tc<2; tc++){
        float bv = qkvb[part*256 + h*32 + tc*16 + l15];
        #pragma unroll
        for(int tm=0; tm<4; tm++){
          #pragma unroll
          for(int r=0; r<4; r++){
            float val = acc[part][tc][tm][r] + bv;
            int tok = tm*16 + g*4 + r;
            int col = tc*16 + l15;  // 0..31
            u16 hv = f2h(val);
            if(part==0)      *(u16*)(Wq + (tok<<6) + ((col<<1) ^ ((tok&3)<<4))) = hv;
            else if(part==1) *(u16*)(Wk + (tok<<6) + ((col<<1) ^ ((tok&3)<<4))) = hv;
            else             *(u16*)(Wv + (col<<7) + ((tok<<1) ^ ((col&7)<<4))) = hv;
          }
        }
      }
    }
  }

  // ---- row norms of q,k (scale folded into q-norm) ----
  {
    float sq = 0.f, sk = 0.f;
    #pragma unroll
    for(int cb=0; cb<4; cb++){
      f16x8 qv = ld16(Wq + (lane<<6) + ((cb<<4) ^ ((lane&3)<<4)));
      f16x8 kv = ld16(Wk + (lane<<6) + ((cb<<4) ^ ((lane&3)<<4)));
      #pragma unroll
      for(int j=0;j<8;j++){ float a=(float)qv[j]; sq+=a*a; float c=(float)kv[j]; sk+=c*c; }
    }
    float sc = __expf(fminf(tsc[h], 4.605170185988091f)); // min(t, ln 100)
    nrmq[lane] = sc / fmaxf(sqrtf(sq), 1e-12f);
    nrmk[lane] = 1.f / fmaxf(sqrtf(sk), 1e-12f);
  }
  __syncthreads();  // all x reads done; X region becomes oall

  // ---- S = q k^T (K=32, one MFMA per 16x16 tile) ----
  f32x4 s[4][4];
  float rsum[4][4];
  {
    f16x8 qf[4], kf[4];
    #pragma unroll
    for(int tm=0; tm<4; tm++){
      int row = tm*16 + l15;
      qf[tm] = ld16(Wq + (row<<6) + ((g<<4) ^ ((row&3)<<4)));
      kf[tm] = ld16(Wk + (row<<6) + ((g<<4) ^ ((row&3)<<4)));
    }
    const f32x4 z4 = {0.f,0.f,0.f,0.f};
    #pragma unroll
    for(int tm=0; tm<4; tm++)
      #pragma unroll
      for(int tn=0; tn<4; tn++)
        s[tm][tn] = mm(qf[tm], kf[tn], z4);
  }
  // ---- epilogue: cosine scale + bias + shift mask, softmax, P->LDS ----
  {
    int idj[4]; float nk[4];
    #pragma unroll
    for(int tn=0; tn<4; tn++){
      int j = tn*16 + l15;
      nk[tn] = nrmk[j];
      int hsj = (wh<<3) + (j>>3), wsj = (wwi<<3) + (j&7);
      idj[tn] = 3*((hsj<56)?0:((hsj<60)?1:2)) + ((wsj<56)?0:((wsj<60)?1:2));
    }
    #pragma unroll
    for(int tm=0; tm<4; tm++){
      #pragma unroll
      for(int r=0; r<4; r++){
        int i = tm*16 + g*4 + r;
        float nq = nrmq[i];
        int hsi = (wh<<3) + (i>>3), wsi = (wwi<<3) + (i&7);
        int idi = 3*((hsi<56)?0:((hsi<60)?1:2)) + ((wsi<56)?0:((wsi<60)?1:2));
        float vr[4];
        #pragma unroll
        for(int tn=0; tn<4; tn++){
          int j = tn*16 + l15;
          float bv = biastab[((h<<6)+i)*64 + j];
          vr[tn] = s[tm][tn][r]*nq*nk[tn] + bv + ((idi!=idj[tn]) ? -100.f : 0.f);
        }
        float mx = fmaxf(fmaxf(vr[0],vr[1]), fmaxf(vr[2],vr[3]));
        mx = fmaxf(mx, __shfl_xor(mx, 1));
        mx = fmaxf(mx, __shfl_xor(mx, 2));
        mx = fmaxf(mx, __shfl_xor(mx, 4));
        mx = fmaxf(mx, __shfl_xor(mx, 8));
        float sumv = 0.f;
        #pragma unroll
        for(int tn=0; tn<4; tn++){
          float p = exp2f((vr[tn]-mx)*1.4426950408889634f);
          sumv += p;
          vr[tn] = p;
        }
        sumv += __shfl_xor(sumv, 1);
        sumv += __shfl_xor(sumv, 2);
        sumv += __shfl_xor(sumv, 4);
        sumv += __shfl_xor(sumv, 8);
        rsum[tm][r] = sumv;
        #pragma unroll
        for(int tn=0; tn<4; tn++){
          int j = tn*16 + l15;
          *(u16*)(Wp + (i<<7) + ((j<<1) ^ ((i&7)<<4))) = f2h(vr[tn]);
        }
      }
    }
  }
  // ---- PV (deferred softmax normalization) ----
  f32x4 o[4][2] = {};
  #pragma unroll
  for(int kk=0; kk<2; kk++){
    f16x8 pf[4];
    #pragma unroll
    for(int tm=0; tm<4; tm++){
      int row = tm*16 + l15;
      pf[tm] = ld16(Wp + (row<<7) + (((kk<<6)+(g<<4)) ^ ((row&7)<<4)));
    }
    #pragma unroll
    for(int tn=0; tn<2; tn++){
      int n = tn*16 + l15;
      f16x8 vf = ld16(Wv + (n<<7) + (((kk<<6)+(g<<4)) ^ ((n&7)<<4)));
      #pragma unroll
      for(int tm=0; tm<4; tm++) o[tm][tn] = mm(pf[tm], vf, o[tm][tn]);
    }
  }
  #pragma unroll
  for(int tm=0; tm<4; tm++)
    #pragma unroll
    for(int tn=0; tn<2; tn++)
      #pragma unroll
      for(int r=0; r<4; r++){
        int i = tm*16 + g*4 + r;
        int col = h*32 + tn*16 + l15;
        float val = o[tm][tn][r] / rsum[tm][r];
        *(u16*)(sm + (i<<9) + ((col<<1) ^ ((i&7)<<4))) = f2h(val);
      }
  __syncthreads();

  // ---- proj -> f32 LDS ----
  {
    float* yr32 = (float*)(sm + 32768);
    f32x4 pa[4][2] = {};
    #pragma unroll
    for(int kk=0; kk<8; kk++){
      f16x8 a[4];
      #pragma unroll
      for(int tm=0; tm<4; tm++){
        int row = tm*16 + l15;
        a[tm] = ld16(sm + (row<<9) + (((kk<<6)+(g<<4)) ^ ((row&7)<<4)));
      }
      #pragma unroll
      for(int tn=0; tn<2; tn++){
        f16x8 bf = ld16(projw + (size_t)(w*16 + tn*8 + kk)*512 + lane*8);
        #pragma unroll
        for(int tm=0; tm<4; tm++) pa[tm][tn] = mm(a[tm], bf, pa[tm][tn]);
      }
    }
    #pragma unroll
    for(int tn=0; tn<2; tn++){
      float pb = projb[w*32 + tn*16 + l15];
      #pragma unroll
      for(int tm=0; tm<4; tm++)
        #pragma unroll
        for(int r=0; r<4; r++){
          int tok = tm*16 + g*4 + r;
          int col = w*32 + tn*16 + l15;
          yr32[tok*256 + (col ^ ((tok&7)<<2))] = pa[tm][tn][r] + pb;
        }
    }
  }
  __syncthreads();

  // ---- fused LN1; write z (fp16) at un-shifted positions ----
  {
    int row = tid >> 3, seg = tid & 7;
    const float* yr = (const float*)(sm + 32768) + row*256;
    int sw4 = (row&7)<<2;
    float yv[32];
    float s1 = 0.f, s2 = 0.f;
    #pragma unroll
    for(int t=0; t<8; t++){
      float4 v4 = *(const float4*)(yr + ((seg*32 + t*4) ^ sw4));
      yv[t*4+0]=v4.x; yv[t*4+1]=v4.y; yv[t*4+2]=v4.z; yv[t*4+3]=v4.w;
      s1 += v4.x+v4.y+v4.z+v4.w;
      s2 += v4.x*v4.x+v4.y*v4.y+v4.z*v4.z+v4.w*v4.w;
    }
    s1 += __shfl_xor(s1,1); s2 += __shfl_xor(s2,1);
    s1 += __shfl_xor(s1,2); s2 += __shfl_xor(s2,2);
    s1 += __shfl_xor(s1,4); s2 += __shfl_xor(s2,4);
    float mean = s1*(1.f/256.f);
    float var = s2*(1.f/256.f) - mean*mean;
    float rstd = rsqrtf(var + 1e-5f);
    u32 hw[16];
    #pragma unroll
    for(int j=0; j<32; j++){
      int c = seg*32 + j;
      float zz = (yv[j]-mean)*rstd*n1w[c] + n1b[c];
      u16 hv = f2h(zz);
      if(j&1) hw[j>>1] |= ((u32)hv)<<16; else hw[j>>1] = (u32)hv;
    }
    int ho = ((wh<<3) + (row>>3) + 4) & 63;
    int wo = ((wwi<<3) + (row&7) + 4) & 63;
    u16* dst = y + (size_t)(b*4096 + ho*64 + wo)*256 + seg*32;
    #pragma unroll
    for(int u2=0; u2<4; u2++)
      ((uint4*)dst)[u2] = *(uint4*)(&hw[u2*4]);
  }
}

// ---------------- K2: xo = x + z; MLP; out = xo + LN2(m) ----------------
// 64 rows/block, 512 threads (2 wm x 4 wn waves, 2 tm each). Hidden in 8 chunks of 128.
// launch_bounds(512,2) = the R4-proven no-spill knob (cap 256, allocator held 96
// cleanly). waves_per_eu(4,4)/(3,3) both collapsed to 64+spill (R10/R11) - dropped.
__global__ __launch_bounds__(512, 2)
void k_mlp(const float* __restrict__ x, const u16* __restrict__ z,
           const u16* __restrict__ fc1, const float* __restrict__ f1b,
           const u16* __restrict__ fc2, const float* __restrict__ f2bb,
           const float* __restrict__ n2w, const float* __restrict__ n2b,
           float* __restrict__ out)
{
  __shared__ char smem[49152];
  char* xo16 = smem;            // [64][512B] fp16 sw8 (32K)
  char* hbf  = smem + 32768;    // [64][256B] fp16 sw8 (16K); lnp aliases later
  const int tid = threadIdx.x;
  const int wv = tid>>6, lane = tid&63, l15 = lane&15, g = lane>>4;
  const int wm = wv>>2, wn = wv&3;
  const size_t row0 = (size_t)blockIdx.x * 64;

  // ---- phase 1: xo = x + z -> fp16 LDS (64 rows, one pass) ----
  {
    int row = tid>>3, seg = tid&7;
    size_t grow = row0 + row;
    const u16* zp = z + grow*256 + seg*32;
    const float* xp = x + grow*256 + seg*32;
    int swb = (row&7)<<4;
    #pragma unroll
    for(int u=0;u<4;u++){
      uint4 raw = ((const uint4*)zp)[u];
      float4 xa = ((const float4*)xp)[2*u];
      float4 xb = ((const float4*)xp)[2*u+1];
      u32 rw[4] = {raw.x, raw.y, raw.z, raw.w};
      float v[8];
      v[0] = xa.x + h2f((u16)(rw[0] & 0xFFFFu));
      v[1] = xa.y + h2f((u16)(rw[0] >> 16));
      v[2] = xa.z + h2f((u16)(rw[1] & 0xFFFFu));
      v[3] = xa.w + h2f((u16)(rw[1] >> 16));
      v[4] = xb.x + h2f((u16)(rw[2] & 0xFFFFu));
      v[5] = xb.y + h2f((u16)(rw[2] >> 16));
      v[6] = xb.z + h2f((u16)(rw[3] & 0xFFFFu));
      v[7] = xb.w + h2f((u16)(rw[3] >> 16));
      u32 pw[4];
      #pragma unroll
      for(int j=0;j<8;j++){
        if(j&1) pw[j>>1] |= ((u32)f2h(v[j]))<<16; else pw[j>>1] = (u32)f2h(v[j]);
      }
      uint4 pk; pk.x=pw[0]; pk.y=pw[1]; pk.z=pw[2]; pk.w=pw[3];
      *(uint4*)(xo16 + (row<<9) + (((seg<<6)+(u<<4)) ^ swb)) = pk;
    }
  }
  __syncthreads();

  // ---- phase 2: 8 chunks of 128 hidden: fc1 -> gelu -> fc2 ----
  f32x4 acc2[2][4] = {};
  for(int ck=0; ck<8; ck++){
    f32x4 a1[2][2] = {{{0.f,0.f,0.f,0.f},{0.f,0.f,0.f,0.f}},
                      {{0.f,0.f,0.f,0.f},{0.f,0.f,0.f,0.f}}};
    {
      const u16* fb = fc1 + ((size_t)(ck*64 + wn*16))*512 + (size_t)lane*8;
      f16x8 bc0 = ld16(fb);             // tn0, kk0
      f16x8 bc1 = ld16(fb + 8*512);     // tn1, kk0
      #pragma unroll
      for(int kk=0; kk<8; kk++){
        f16x8 nb0, nb1;
        if(kk < 7){
          nb0 = ld16(fb + (size_t)(kk+1)*512);
          nb1 = ld16(fb + (size_t)(8+kk+1)*512);
        }
        f16x8 af0, af1;
        {
          int row = wm*32 + l15;
          af0 = ld16(xo16 + (row<<9) + (((kk<<6)+(g<<4)) ^ ((row&7)<<4)));
          row = wm*32 + 16 + l15;
          af1 = ld16(xo16 + (row<<9) + (((kk<<6)+(g<<4)) ^ ((row&7)<<4)));
        }
        a1[0][0] = mm(af0, bc0, a1[0][0]);
        a1[1][0] = mm(af1, bc0, a1[1][0]);
        a1[0][1] = mm(af0, bc1, a1[0][1]);
        a1[1][1] = mm(af1, bc1, a1[1][1]);
        bc0 = nb0; bc1 = nb1;
      }
    }
    #pragma unroll
    for(int tn=0;tn<2;tn++){
      float bv = f1b[ck*128 + wn*32 + tn*16 + l15];
      #pragma unroll
      for(int tm=0;tm<2;tm++)
        #pragma unroll
        for(int r=0;r<4;r++){
          float zv = a1[tm][tn][r] + bv;
          float u0 = 0.7978845608028654f*(zv + 0.044715f*zv*zv*zv);
          float e = exp2f(u0 * 2.8853900817779268f);   // e^(2u)
          float th = 1.f - 2.f/(e+1.f);
          float ge = 0.5f*zv*(1.f+th);
          int row = wm*32 + tm*16 + g*4 + r;
          int hc = wn*32 + tn*16 + l15;                // 0..127
          *(u16*)(hbf + (row<<8) + ((hc<<1) ^ ((row&7)<<4))) = f2h(ge);
        }
    }
    __syncthreads();
    {
      const u16* gb = fc2 + ((size_t)(wn*128 + ck*4))*512 + (size_t)lane*8;
      f16x8 c0 = ld16(gb);
      f16x8 c1 = ld16(gb + 32*512);
      f16x8 c2 = ld16(gb + 64*512);
      f16x8 c3 = ld16(gb + 96*512);
      #pragma unroll
      for(int kk2=0; kk2<4; kk2++){
        f16x8 n0,n1,n2,n3;
        if(kk2 < 3){
          n0 = ld16(gb + (size_t)(kk2+1)*512);
          n1 = ld16(gb + (size_t)(32+kk2+1)*512);
          n2 = ld16(gb + (size_t)(64+kk2+1)*512);
          n3 = ld16(gb + (size_t)(96+kk2+1)*512);
        }
        f16x8 af0, af1;
        {
          int row = wm*32 + l15;
          af0 = ld16(hbf + (row<<8) + (((kk2<<6)+(g<<4)) ^ ((row&7)<<4)));
          row = wm*32 + 16 + l15;
          af1 = ld16(hbf + (row<<8) + (((kk2<<6)+(g<<4)) ^ ((row&7)<<4)));
        }
        acc2[0][0] = mm(af0, c0, acc2[0][0]);
        acc2[1][0] = mm(af1, c0, acc2[1][0]);
        acc2[0][1] = mm(af0, c1, acc2[0][1]);
        acc2[1][1] = mm(af1, c1, acc2[1][1]);
        acc2[0][2] = mm(af0, c2, acc2[0][2]);
        acc2[1][2] = mm(af1, c2, acc2[1][2]);
        acc2[0][3] = mm(af0, c3, acc2[0][3]);
        acc2[1][3] = mm(af1, c3, acc2[1][3]);
        c0=n0; c1=n1; c2=n2; c3=n3;
      }
    }
    __syncthreads();
  }

  // ---- phase 3: + fc2_b, block-wide LN2, out = xo + LN2(m) ----
  {
    float b2v[4], w2v[4], b2n[4];
    #pragma unroll
    for(int tn=0;tn<4;tn++){
      int col = wn*64 + tn*16 + l15;
      b2v[tn] = f2bb[col];
      w2v[tn] = n2w[col];
      b2n[tn] = n2b[col];
    }
    #pragma unroll
    for(int tm=0;tm<2;tm++)
      #pragma unroll
      for(int tn=0;tn<4;tn++)
        #pragma unroll
        for(int r=0;r<4;r++) acc2[tm][tn][r] += b2v[tn];

    float* lnp = (float*)hbf;   // [64][4][2] f32 = 2K, safe after final barrier
    #pragma unroll
    for(int tm=0;tm<2;tm++)
      #pragma unroll
      for(int r=0;r<4;r++){
        float sA=0.f, sB=0.f;
        #pragma unroll
        for(int tn=0;tn<4;tn++){ float v=acc2[tm][tn][r]; sA+=v; sB+=v*v; }
        sA += __shfl_xor(sA,1); sB += __shfl_xor(sB,1);
        sA += __shfl_xor(sA,2); sB += __shfl_xor(sB,2);
        sA += __shfl_xor(sA,4); sB += __shfl_xor(sB,4);
        sA += __shfl_xor(sA,8); sB += __shfl_xor(sB,8);
        if(l15==0){
          int row = wm*32 + tm*16 + g*4 + r;
          lnp[(row*4+wn)*2]   = sA;
          lnp[(row*4+wn)*2+1] = sB;
        }
      }
    __syncthreads();
    #pragma unroll
    for(int tm=0;tm<2;tm++)
      #pragma unroll
      for(int r=0;r<4;r++){
        int row = wm*32 + tm*16 + g*4 + r;
        float S=0.f, SS=0.f;
        #pragma unroll
        for(int q2=0;q2<4;q2++){ S += lnp[(row*4+q2)*2]; SS += lnp[(row*4+q2)*2+1]; }
        float mean = S*(1.f/256.f);
        float var = SS*(1.f/256.f) - mean*mean;
        float rstd = rsqrtf(var + 1e-5f);
        float* op = out + (row0 + row)*256;
        #pragma unroll
        for(int tn=0;tn<4;tn++){
          int col = wn*64 + tn*16 + l15;
          float xo = h2f(*(const u16*)(xo16 + (row<<9) + ((col<<1) ^ ((row&7)<<4))));
          op[col] = xo + (acc2[tm][tn][r]-mean)*rstd*w2v[tn] + b2n[tn];
        }
      }
  }
}

extern "C" void kernel_launch(void* const* d_in, const int* in_sizes, int n_in,
                              void* d_out, int out_size, void* d_ws, size_t ws_size,
                              hipStream_t stream)
{
  const float* x     = (const float*)d_in[0];
  const float* qkvw  = (const float*)d_in[1];
  const float* qkvb  = (const float*)d_in[2];
  const float* projw = (const float*)d_in[3];
  const float* projb = (const float*)d_in[4];
  const float* tsc   = (const float*)d_in[5];
  const float* w1    = (const float*)d_in[6];
  const float* b1    = (const float*)d_in[7];
  const float* w2    = (const float*)d_in[8];
  const float* n1w   = (const float*)d_in[9];
  const float* n1b   = (const float*)d_in[10];
  const float* n2w   = (const float*)d_in[11];
  const float* n2b   = (const float*)d_in[12];
  const float* fc1w  = (const float*)d_in[13];
  const float* fc1b  = (const float*)d_in[14];
  const float* fc2w  = (const float*)d_in[15];
  const float* fc2b  = (const float*)d_in[16];
  float* out = (float*)d_out;

  char* ws = (char*)d_ws;
  const size_t WB = 134217728;  // z fp16 buffer (64*4096*256*2)
  u16* z_h      = (u16*)(ws);
  u16* qkvw_h   = (u16*)(ws + WB);
  u16* projw_h  = (u16*)(ws + WB + 393216);
  u16* fc1_h    = (u16*)(ws + WB + 524288);
  u16* fc2_h    = (u16*)(ws + WB + 1048576);
  float* biastab= (float*)(ws + WB + 1572864);

  (void)hipFuncSetAttribute((const void*)k_attn,
                      hipFuncAttributeMaxDynamicSharedMemorySize, 135168);

  k_wconv<<<384, 256, 0, stream>>>(qkvw, projw, fc1w, fc2w,
                                   qkvw_h, projw_h, fc1_h, fc2_h);
  k_bias<<<1, 256, 0, stream>>>(w1, b1, w2, biastab);
  k_attn<<<4096, 512, 135168, stream>>>(x, qkvw_h, qkvb, projw_h, projb,
                                        tsc, biastab, n1w, n1b, z_h);
  k_mlp<<<4096, 512, 0, stream>>>(x, z_h, fc1_h, fc1b,
                                  fc2_h, fc2b, n2w, n2b, out);
}

// Round 14
// 1013.371 us; speedup vs baseline: 1.7387x; 1.7387x over previous
//
#include <hip/hip_runtime.h>

typedef float f32x4 __attribute__((ext_vector_type(4)));
typedef _Float16 f16;
typedef _Float16 f16x8 __attribute__((ext_vector_type(8)));
typedef unsigned int u32;
typedef unsigned short u16;

__device__ __forceinline__ u16 f2h(float f){
  f16 h = (f16)f; return __builtin_bit_cast(u16, h);
}
__device__ __forceinline__ float h2f(u16 u){
  f16 h = __builtin_bit_cast(f16, u); return (float)h;
}
__device__ __forceinline__ f16x8 ld16(const void* p){
  uint4 v = *(const uint4*)p;
  return __builtin_bit_cast(f16x8, v);
}
__device__ __forceinline__ f32x4 mm(f16x8 a, f16x8 b, f32x4 c){
  return __builtin_amdgcn_mfma_f32_16x16x32_f16(a, b, c, 0, 0, 0);
}

// ---------------- K0a: weights -> fp16, MFMA-fragment-major layout ----------------
// Fragment = 16 out-cols x 32 k; storage frag*512 + lane*8, elem j = W[col0+l15][k0+g*8+j].
__global__ void k_wconv(const float* __restrict__ qkvw, const float* __restrict__ projw,
                        const float* __restrict__ fc1w, const float* __restrict__ fc2w,
                        u16* __restrict__ o_qkv, u16* __restrict__ o_proj,
                        u16* __restrict__ o_fc1, u16* __restrict__ o_fc2){
  int t = blockIdx.x*256 + threadIdx.x;      // 1536 frags * 64 lanes = 98304
  int frag = t >> 6, lane = t & 63;
  int l15 = lane & 15, g = lane >> 4;
  const float* src; u16* dst; int col, k, ld, f;
  if(frag < 384){                             // qkv: frag = part*128 + h*16 + tc*8 + kk
    f = frag;
    int part = f >> 7, rem = f & 127;
    int h = rem >> 4, rem2 = rem & 15;
    int tc = rem2 >> 3, kk = rem2 & 7;
    col = part*256 + h*32 + tc*16 + l15; k = kk*32 + g*8;
    src = qkvw; dst = o_qkv; ld = 256;
  } else if(frag < 512){                      // proj: frag = w8*16 + tn2*8 + kk
    f = frag - 384;
    int w8 = f >> 4, rem = f & 15;
    int tn2 = rem >> 3, kk = rem & 7;
    col = w8*32 + tn2*16 + l15; k = kk*32 + g*8;
    src = projw; dst = o_proj; ld = 256;
  } else if(frag < 1024){                     // fc1: frag = ck*64 + wn8*8 + kk (128-col chunks)
    f = frag - 512;
    int ck = f >> 6, rem = f & 63;
    int wn8 = rem >> 3, kk = rem & 7;
    col = ck*128 + wn8*16 + l15; k = kk*32 + g*8;
    src = fc1w; dst = o_fc1; ld = 256;
  } else {                                    // fc2: frag = wn*128 + tn*32 + ck*4 + kk2 (128-k chunks)
    f = frag - 1024;
    int wn = f >> 7, rem = f & 127;
    int tn = rem >> 5, rem2 = rem & 31;
    int ck = rem2 >> 2, kk2 = rem2 & 3;
    col = wn*64 + tn*16 + l15; k = ck*128 + kk2*32 + g*8;
    src = fc2w; dst = o_fc2; ld = 1024;
  }
  float4 a = *(const float4*)(src + (size_t)col*ld + k);
  float4 b4 = *(const float4*)(src + (size_t)col*ld + k + 4);
  ushort4 h0, h1;
  h0.x=f2h(a.x); h0.y=f2h(a.y); h0.z=f2h(a.z); h0.w=f2h(a.w);
  h1.x=f2h(b4.x); h1.y=f2h(b4.y); h1.z=f2h(b4.z); h1.w=f2h(b4.w);
  u16* o = dst + (size_t)f*512 + lane*8;
  *(ushort4*)o = h0;
  *(ushort4*)(o+4) = h1;
}

// ---------------- K0b: CRPB bias table (8,64,64) ----------------
__global__ void k_bias(const float* __restrict__ w1, const float* __restrict__ b1,
                       const float* __restrict__ w2, float* __restrict__ bias){
  __shared__ float tab[225][8];
  int t = threadIdx.x;
  if(t < 225){
    int i15 = t/15, j15 = t%15;
    float di = (float)(i15-7) * (8.f/7.f);
    float dj = (float)(j15-7) * (8.f/7.f);
    float vi = copysignf(log2f(fabsf(di)+1.f)*(1.f/3.f), di);
    float vj = copysignf(log2f(fabsf(dj)+1.f)*(1.f/3.f), dj);
    float acc[8];
    #pragma unroll
    for(int h=0;h<8;h++) acc[h]=0.f;
    for(int c=0;c<384;c++){
      float hv = vi*w1[c*2] + vj*w1[c*2+1] + b1[c];
      hv = fmaxf(hv, 0.f);
      #pragma unroll
      for(int h=0;h<8;h++) acc[h] += hv * w2[h*384+c];
    }
    #pragma unroll
    for(int h=0;h<8;h++) tab[t][h] = acc[h];
  }
  __syncthreads();
  for(int pr = t; pr < 4096; pr += 256){
    int i = pr>>6, j = pr&63;
    int dh = (i>>3)-(j>>3)+7, dw = (i&7)-(j&7)+7;
    int idx = dh*15+dw;
    #pragma unroll
    for(int h=0;h<8;h++){
      float v = tab[idx][h];
      bias[(h*64+i)*64+j] = 16.f / (1.f + __expf(-v));
    }
  }
}

// ---------------- K1: fused shifted-window attention + LN1 ----------------
// R6 structure + merged single-kk-loop QKV (R13, ~-120us vs split loops).
__global__ __launch_bounds__(512, 1)
void k_attn(const float* __restrict__ x, const u16* __restrict__ qkvw,
            const float* __restrict__ qkvb, const u16* __restrict__ projw,
            const float* __restrict__ projb, const float* __restrict__ tsc,
            const float* __restrict__ biastab,
            const float* __restrict__ n1w, const float* __restrict__ n1b,
            u16* __restrict__ y)
{
  extern __shared__ char sm[];
  const int tid = threadIdx.x;
  const int w = tid >> 6, lane = tid & 63;
  const int l15 = lane & 15, g = lane >> 4;
  const int blk = blockIdx.x;
  const int b = blk >> 6, nw = blk & 63, wh = nw >> 3, wwi = nw & 7;

  char* Wq = sm + 32768 + w*12288;
  char* Wk = Wq + 4096;
  char* Wv = Wq + 8192;
  char* Wp = Wq;  // aliases q+k after S fragments are in registers
  float* nrmq = (float*)(sm + 131072 + w*512);
  float* nrmk = nrmq + 64;

  // ---- stage shifted x window -> fp16 LDS ----
  {
    int row = tid >> 3, seg = tid & 7;
    int hs = ((wh<<3) + (row>>3) + 4) & 63;
    int ws_ = ((wwi<<3) + (row&7) + 4) & 63;
    const float* src = x + (size_t)(b*4096 + hs*64 + ws_)*256 + seg*32;
    char* drow = sm + row*512;
    int sw = (row & 7) << 4;
    #pragma unroll
    for(int u=0; u<4; u++){
      float4 f0 = ((const float4*)src)[2*u];
      float4 f1 = ((const float4*)src)[2*u+1];
      uint4 pk;
      pk.x = (u32)f2h(f0.x) | ((u32)f2h(f0.y)<<16);
      pk.y = (u32)f2h(f0.z) | ((u32)f2h(f0.w)<<16);
      pk.z = (u32)f2h(f1.x) | ((u32)f2h(f1.y)<<16);
      pk.w = (u32)f2h(f1.z) | ((u32)f2h(f1.w)<<16);
      *(uint4*)(drow + (((seg<<6) + (u<<4)) ^ sw)) = pk;
    }
  }
  __syncthreads();

  const int h = w;  // one head per wave
  // ---- QKV GEMM, single kk loop over all 3 parts ----
  {
    f32x4 acc[3][2][4] = {};
    #pragma unroll
    for(int kk=0; kk<8; kk++){
      f16x8 a[4];
      #pragma unroll
      for(int tm=0; tm<4; tm++){
        int row = tm*16 + l15;
        a[tm] = ld16(sm + row*512 + (((kk<<6) + (g<<4)) ^ ((row&7)<<4)));
      }
      #pragma unroll
      for(int part=0; part<3; part++){
        #pragma unroll
        for(int tc=0; tc<2; tc++){
          f16x8 bf = ld16(qkvw + (size_t)(part*128 + h*16 + tc*8 + kk)*512 + lane*8);
          #pragma unroll
          for(int tm=0; tm<4; tm++) acc[part][tc][tm] = mm(a[tm], bf, acc[part][tc][tm]);
        }
      }
    }
    #pragma unroll
    for(int part=0; part<3; part++){
      #pragma unroll
      for(int tc=0; tc<2; tc++){
        float bv = qkvb[part*256 + h*32 + tc*16 + l15];
        #pragma unroll
        for(int tm=0; tm<4; tm++){
          #pragma unroll
          for(int r=0; r<4; r++){
            float val = acc[part][tc][tm][r] + bv;
            int tok = tm*16 + g*4 + r;
            int col = tc*16 + l15;  // 0..31
            u16 hv = f2h(val);
            if(part==0)      *(u16*)(Wq + (tok<<6) + ((col<<1) ^ ((tok&3)<<4))) = hv;
            else if(part==1) *(u16*)(Wk + (tok<<6) + ((col<<1) ^ ((tok&3)<<4))) = hv;
            else             *(u16*)(Wv + (col<<7) + ((tok<<1) ^ ((col&7)<<4))) = hv;
          }
        }
      }
    }
  }

  // ---- row norms of q,k (scale folded into q-norm) ----
  {
    float sq = 0.f, sk = 0.f;
    #pragma unroll
    for(int cb=0; cb<4; cb++){
      f16x8 qv = ld16(Wq + (lane<<6) + ((cb<<4) ^ ((lane&3)<<4)));
      f16x8 kv = ld16(Wk + (lane<<6) + ((cb<<4) ^ ((lane&3)<<4)));
      #pragma unroll
      for(int j=0;j<8;j++){ float a=(float)qv[j]; sq+=a*a; float c=(float)kv[j]; sk+=c*c; }
    }
    float sc = __expf(fminf(tsc[h], 4.605170185988091f)); // min(t, ln 100)
    nrmq[lane] = sc / fmaxf(sqrtf(sq), 1e-12f);
    nrmk[lane] = 1.f / fmaxf(sqrtf(sk), 1e-12f);
  }
  __syncthreads();  // all x reads done; X region becomes oall

  // ---- S = q k^T (K=32, one MFMA per 16x16 tile) ----
  f32x4 s[4][4];
  float rsum[4][4];
  {
    f16x8 qf[4], kf[4];
    #pragma unroll
    for(int tm=0; tm<4; tm++){
      int row = tm*16 + l15;
      qf[tm] = ld16(Wq + (row<<6) + ((g<<4) ^ ((row&3)<<4)));
      kf[tm] = ld16(Wk + (row<<6) + ((g<<4) ^ ((row&3)<<4)));
    }
    const f32x4 z4 = {0.f,0.f,0.f,0.f};
    #pragma unroll
    for(int tm=0; tm<4; tm++)
      #pragma unroll
      for(int tn=0; tn<4; tn++)
        s[tm][tn] = mm(qf[tm], kf[tn], z4);
  }
  // ---- epilogue: cosine scale + bias + shift mask, softmax, P->LDS ----
  {
    int idj[4]; float nk[4];
    #pragma unroll
    for(int tn=0; tn<4; tn++){
      int j = tn*16 + l15;
      nk[tn] = nrmk[j];
      int hsj = (wh<<3) + (j>>3), wsj = (wwi<<3) + (j&7);
      idj[tn] = 3*((hsj<56)?0:((hsj<60)?1:2)) + ((wsj<56)?0:((wsj<60)?1:2));
    }
    #pragma unroll
    for(int tm=0; tm<4; tm++){
      #pragma unroll
      for(int r=0; r<4; r++){
        int i = tm*16 + g*4 + r;
        float nq = nrmq[i];
        int hsi = (wh<<3) + (i>>3), wsi = (wwi<<3) + (i&7);
        int idi = 3*((hsi<56)?0:((hsi<60)?1:2)) + ((wsi<56)?0:((wsi<60)?1:2));
        float vr[4];
        #pragma unroll
        for(int tn=0; tn<4; tn++){
          int j = tn*16 + l15;
          float bv = biastab[((h<<6)+i)*64 + j];
          vr[tn] = s[tm][tn][r]*nq*nk[tn] + bv + ((idi!=idj[tn]) ? -100.f : 0.f);
        }
        float mx = fmaxf(fmaxf(vr[0],vr[1]), fmaxf(vr[2],vr[3]));
        mx = fmaxf(mx, __shfl_xor(mx, 1));
        mx = fmaxf(mx, __shfl_xor(mx, 2));
        mx = fmaxf(mx, __shfl_xor(mx, 4));
        mx = fmaxf(mx, __shfl_xor(mx, 8));
        float sumv = 0.f;
        #pragma unroll
        for(int tn=0; tn<4; tn++){
          float p = exp2f((vr[tn]-mx)*1.4426950408889634f);
          sumv += p;
          vr[tn] = p;
        }
        sumv += __shfl_xor(sumv, 1);
        sumv += __shfl_xor(sumv, 2);
        sumv += __shfl_xor(sumv, 4);
        sumv += __shfl_xor(sumv, 8);
        rsum[tm][r] = sumv;
        #pragma unroll
        for(int tn=0; tn<4; tn++){
          int j = tn*16 + l15;
          *(u16*)(Wp + (i<<7) + ((j<<1) ^ ((i&7)<<4))) = f2h(vr[tn]);
        }
      }
    }
  }
  // ---- PV (deferred softmax normalization) ----
  f32x4 o[4][2] = {};
  #pragma unroll
  for(int kk=0; kk<2; kk++){
    f16x8 pf[4];
    #pragma unroll
    for(int tm=0; tm<4; tm++){
      int row = tm*16 + l15;
      pf[tm] = ld16(Wp + (row<<7) + (((kk<<6)+(g<<4)) ^ ((row&7)<<4)));
    }
    #pragma unroll
    for(int tn=0; tn<2; tn++){
      int n = tn*16 + l15;
      f16x8 vf = ld16(Wv + (n<<7) + (((kk<<6)+(g<<4)) ^ ((n&7)<<4)));
      #pragma unroll
      for(int tm=0; tm<4; tm++) o[tm][tn] = mm(pf[tm], vf, o[tm][tn]);
    }
  }
  #pragma unroll
  for(int tm=0; tm<4; tm++)
    #pragma unroll
    for(int tn=0; tn<2; tn++)
      #pragma unroll
      for(int r=0; r<4; r++){
        int i = tm*16 + g*4 + r;
        int col = h*32 + tn*16 + l15;
        float val = o[tm][tn][r] / rsum[tm][r];
        *(u16*)(sm + (i<<9) + ((col<<1) ^ ((i&7)<<4))) = f2h(val);
      }
  __syncthreads();

  // ---- proj -> f32 LDS ----
  {
    float* yr32 = (float*)(sm + 32768);
    f32x4 pa[4][2] = {};
    #pragma unroll
    for(int kk=0; kk<8; kk++){
      f16x8 a[4];
      #pragma unroll
      for(int tm=0; tm<4; tm++){
        int row = tm*16 + l15;
        a[tm] = ld16(sm + (row<<9) + (((kk<<6)+(g<<4)) ^ ((row&7)<<4)));
      }
      #pragma unroll
      for(int tn=0; tn<2; tn++){
        f16x8 bf = ld16(projw + (size_t)(w*16 + tn*8 + kk)*512 + lane*8);
        #pragma unroll
        for(int tm=0; tm<4; tm++) pa[tm][tn] = mm(a[tm], bf, pa[tm][tn]);
      }
    }
    #pragma unroll
    for(int tn=0; tn<2; tn++){
      float pb = projb[w*32 + tn*16 + l15];
      #pragma unroll
      for(int tm=0; tm<4; tm++)
        #pragma unroll
        for(int r=0; r<4; r++){
          int tok = tm*16 + g*4 + r;
          int col = w*32 + tn*16 + l15;
          yr32[tok*256 + (col ^ ((tok&7)<<2))] = pa[tm][tn][r] + pb;
        }
    }
  }
  __syncthreads();

  // ---- fused LN1; write z (fp16) at un-shifted positions ----
  {
    int row = tid >> 3, seg = tid & 7;
    const float* yr = (const float*)(sm + 32768) + row*256;
    int sw4 = (row&7)<<2;
    float yv[32];
    float s1 = 0.f, s2 = 0.f;
    #pragma unroll
    for(int t=0; t<8; t++){
      float4 v4 = *(const float4*)(yr + ((seg*32 + t*4) ^ sw4));
      yv[t*4+0]=v4.x; yv[t*4+1]=v4.y; yv[t*4+2]=v4.z; yv[t*4+3]=v4.w;
      s1 += v4.x+v4.y+v4.z+v4.w;
      s2 += v4.x*v4.x+v4.y*v4.y+v4.z*v4.z+v4.w*v4.w;
    }
    s1 += __shfl_xor(s1,1); s2 += __shfl_xor(s2,1);
    s1 += __shfl_xor(s1,2); s2 += __shfl_xor(s2,2);
    s1 += __shfl_xor(s1,4); s2 += __shfl_xor(s2,4);
    float mean = s1*(1.f/256.f);
    float var = s2*(1.f/256.f) - mean*mean;
    float rstd = rsqrtf(var + 1e-5f);
    u32 hw[16];
    #pragma unroll
    for(int j=0; j<32; j++){
      int c = seg*32 + j;
      float zz = (yv[j]-mean)*rstd*n1w[c] + n1b[c];
      u16 hv = f2h(zz);
      if(j&1) hw[j>>1] |= ((u32)hv)<<16; else hw[j>>1] = (u32)hv;
    }
    int ho = ((wh<<3) + (row>>3) + 4) & 63;
    int wo = ((wwi<<3) + (row&7) + 4) & 63;
    u16* dst = y + (size_t)(b*4096 + ho*64 + wo)*256 + seg*32;
    #pragma unroll
    for(int u2=0; u2<4; u2++)
      ((uint4*)dst)[u2] = *(uint4*)(&hw[u2*4]);
  }
}

// ---------------- K2: xo = x + z; MLP; out = xo + LN2(m) ----------------
// R6 config restored: 32 rows/block, 256 threads (4 N-waves), 8 chunks of 128,
// 24K LDS, waves_per_eu(4,4). Measured ~450us across R6/R8/R9 = at the L2-BW
// floor (8192 blocks x 2MB weights = 16GB / 34.5TB/s = 464us). All 64-row
// variants lost more to the register allocator than they saved in L2 traffic
// (R10 84+spill 650, R11 64+spill 589, R12 LDS-bound 745, R13 1-block/CU 1293).
__global__ __attribute__((amdgpu_waves_per_eu(4,4))) __launch_bounds__(256)
void k_mlp(const float* __restrict__ x, const u16* __restrict__ z,
           const u16* __restrict__ fc1, const float* __restrict__ f1b,
           const u16* __restrict__ fc2, const float* __restrict__ f2bb,
           const float* __restrict__ n2w, const float* __restrict__ n2b,
           float* __restrict__ out)
{
  __shared__ char smem[24576];
  char* xo16 = smem;            // [32][512B] fp16 sw8
  char* hbf  = smem + 16384;    // [32][256B] fp16 sw8 (128 cols/chunk); lnp aliases later
  const int tid = threadIdx.x;
  const int wn = tid>>6, lane = tid&63, l15 = lane&15, g = lane>>4;
  const size_t row0 = (size_t)blockIdx.x * 32;

  // ---- phase 1: xo = x + z -> fp16 LDS ----
  {
    int row = tid>>3, seg = tid&7;
    size_t grow = row0 + row;
    const u16* zp = z + grow*256 + seg*32;
    const float* xp = x + grow*256 + seg*32;
    int swb = (row&7)<<4;
    #pragma unroll
    for(int u=0;u<4;u++){
      uint4 raw = ((const uint4*)zp)[u];
      float4 xa = ((const float4*)xp)[2*u];
      float4 xb = ((const float4*)xp)[2*u+1];
      u32 rw[4] = {raw.x, raw.y, raw.z, raw.w};
      float v[8];
      v[0] = xa.x + h2f((u16)(rw[0] & 0xFFFFu));
      v[1] = xa.y + h2f((u16)(rw[0] >> 16));
      v[2] = xa.z + h2f((u16)(rw[1] & 0xFFFFu));
      v[3] = xa.w + h2f((u16)(rw[1] >> 16));
      v[4] = xb.x + h2f((u16)(rw[2] & 0xFFFFu));
      v[5] = xb.y + h2f((u16)(rw[2] >> 16));
      v[6] = xb.z + h2f((u16)(rw[3] & 0xFFFFu));
      v[7] = xb.w + h2f((u16)(rw[3] >> 16));
      u32 pw[4];
      #pragma unroll
      for(int j=0;j<8;j++){
        if(j&1) pw[j>>1] |= ((u32)f2h(v[j]))<<16; else pw[j>>1] = (u32)f2h(v[j]);
      }
      uint4 pk; pk.x=pw[0]; pk.y=pw[1]; pk.z=pw[2]; pk.w=pw[3];
      *(uint4*)(xo16 + (row<<9) + (((seg<<6)+(u<<4)) ^ swb)) = pk;
    }
  }
  __syncthreads();

  // ---- phase 2: 8 chunks of 128 hidden: fc1 -> gelu -> fc2 ----
  f32x4 acc2[2][2] = {};
  f32x4 acc2b[2][2] = {};
  for(int ck=0; ck<8; ck++){
    // fc1 GEMM: out cols ck*128 + wn*32 + {0..31}, K=256
    f32x4 a1[2][2] = {{{0.f,0.f,0.f,0.f},{0.f,0.f,0.f,0.f}},
                      {{0.f,0.f,0.f,0.f},{0.f,0.f,0.f,0.f}}};
    {
      const u16* fb = fc1 + ((size_t)(ck*64 + wn*16))*512 + (size_t)lane*8;
      f16x8 bc0 = ld16(fb);             // tn0, kk0
      f16x8 bc1 = ld16(fb + 8*512);     // tn1, kk0
      #pragma unroll
      for(int kk=0; kk<8; kk++){
        f16x8 nb0, nb1;
        if(kk < 7){
          nb0 = ld16(fb + (size_t)(kk+1)*512);
          nb1 = ld16(fb + (size_t)(8+kk+1)*512);
        }
        f16x8 af0, af1;
        {
          int row = l15;
          af0 = ld16(xo16 + (row<<9) + (((kk<<6)+(g<<4)) ^ ((row&7)<<4)));
          row = 16 + l15;
          af1 = ld16(xo16 + (row<<9) + (((kk<<6)+(g<<4)) ^ ((row&7)<<4)));
        }
        a1[0][0] = mm(af0, bc0, a1[0][0]);
        a1[1][0] = mm(af1, bc0, a1[1][0]);
        a1[0][1] = mm(af0, bc1, a1[0][1]);
        a1[1][1] = mm(af1, bc1, a1[1][1]);
        bc0 = nb0; bc1 = nb1;
      }
    }
    // GELU -> hbf [32][128] fp16 sw8 (local cols of this chunk)
    #pragma unroll
    for(int tn=0;tn<2;tn++){
      float bv = f1b[ck*128 + wn*32 + tn*16 + l15];
      #pragma unroll
      for(int tm=0;tm<2;tm++)
        #pragma unroll
        for(int r=0;r<4;r++){
          float zv = a1[tm][tn][r] + bv;
          float u0 = 0.7978845608028654f*(zv + 0.044715f*zv*zv*zv);
          float e = exp2f(u0 * 2.8853900817779268f);   // e^(2u)
          float th = 1.f - 2.f/(e+1.f);
          float ge = 0.5f*zv*(1.f+th);
          int row = tm*16 + g*4 + r;
          int hc = wn*32 + tn*16 + l15;                // 0..127
          *(u16*)(hbf + (row<<8) + ((hc<<1) ^ ((row&7)<<4))) = f2h(ge);
        }
    }
    __syncthreads();
    // fc2 GEMM: K-chunk ck*128, out cols wn*64 + {0..63}
    {
      const u16* gb = fc2 + ((size_t)(wn*128 + ck*4))*512 + (size_t)lane*8;
      f16x8 c0 = ld16(gb);               // tn0 kk2=0
      f16x8 c1 = ld16(gb + 32*512);      // tn1
      f16x8 c2 = ld16(gb + 64*512);      // tn2
      f16x8 c3 = ld16(gb + 96*512);      // tn3
      #pragma unroll
      for(int kk2=0; kk2<4; kk2++){
        f16x8 n0,n1,n2,n3;
        if(kk2 < 3){
          n0 = ld16(gb + (size_t)(kk2+1)*512);
          n1 = ld16(gb + (size_t)(32+kk2+1)*512);
          n2 = ld16(gb + (size_t)(64+kk2+1)*512);
          n3 = ld16(gb + (size_t)(96+kk2+1)*512);
        }
        f16x8 af0, af1;
        {
          int row = l15;
          af0 = ld16(hbf + (row<<8) + (((kk2<<6)+(g<<4)) ^ ((row&7)<<4)));
          row = 16 + l15;
          af1 = ld16(hbf + (row<<8) + (((kk2<<6)+(g<<4)) ^ ((row&7)<<4)));
        }
        acc2[0][0] = mm(af0, c0, acc2[0][0]);
        acc2[1][0] = mm(af1, c0, acc2[1][0]);
        acc2[0][1] = mm(af0, c1, acc2[0][1]);
        acc2[1][1] = mm(af1, c1, acc2[1][1]);
        acc2b[0][0] = mm(af0, c2, acc2b[0][0]);
        acc2b[1][0] = mm(af1, c2, acc2b[1][0]);
        acc2b[0][1] = mm(af0, c3, acc2b[0][1]);
        acc2b[1][1] = mm(af1, c3, acc2b[1][1]);
        c0=n0; c1=n1; c2=n2; c3=n3;
      }
    }
    __syncthreads();
  }

  // ---- phase 3: + fc2_b, block-wide LN2, out = xo + LN2(m) ----
  {
    float b2v[4], w2v[4], b2n[4];
    #pragma unroll
    for(int tn=0;tn<4;tn++){
      int col = wn*64 + tn*16 + l15;
      b2v[tn] = f2bb[col];
      w2v[tn] = n2w[col];
      b2n[tn] = n2b[col];
    }
    #pragma unroll
    for(int tm=0;tm<2;tm++)
      #pragma unroll
      for(int r=0;r<4;r++){
        acc2[tm][0][r]  += b2v[0];
        acc2[tm][1][r]  += b2v[1];
        acc2b[tm][0][r] += b2v[2];
        acc2b[tm][1][r] += b2v[3];
      }

    float* lnp = (float*)hbf;   // [32][4][2] f32, safe after final barrier above
    #pragma unroll
    for(int tm=0;tm<2;tm++)
      #pragma unroll
      for(int r=0;r<4;r++){
        float v0=acc2[tm][0][r], v1=acc2[tm][1][r], v2=acc2b[tm][0][r], v3=acc2b[tm][1][r];
        float sA = v0+v1+v2+v3;
        float sB = v0*v0+v1*v1+v2*v2+v3*v3;
        sA += __shfl_xor(sA,1); sB += __shfl_xor(sB,1);
        sA += __shfl_xor(sA,2); sB += __shfl_xor(sB,2);
        sA += __shfl_xor(sA,4); sB += __shfl_xor(sB,4);
        sA += __shfl_xor(sA,8); sB += __shfl_xor(sB,8);
        if(l15==0){
          int row = tm*16 + g*4 + r;
          lnp[(row*4+wn)*2]   = sA;
          lnp[(row*4+wn)*2+1] = sB;
        }
      }
    __syncthreads();
    #pragma unroll
    for(int tm=0;tm<2;tm++)
      #pragma unroll
      for(int r=0;r<4;r++){
        int row = tm*16 + g*4 + r;
        float S=0.f, SS=0.f;
        #pragma unroll
        for(int q2=0;q2<4;q2++){ S += lnp[(row*4+q2)*2]; SS += lnp[(row*4+q2)*2+1]; }
        float mean = S*(1.f/256.f);
        float var = SS*(1.f/256.f) - mean*mean;
        float rstd = rsqrtf(var + 1e-5f);
        float* op = out + (row0 + row)*256;
        float mv[4] = {acc2[tm][0][r], acc2[tm][1][r], acc2b[tm][0][r], acc2b[tm][1][r]};
        #pragma unroll
        for(int tn=0;tn<4;tn++){
          int col = wn*64 + tn*16 + l15;
          float xo = h2f(*(const u16*)(xo16 + (row<<9) + ((col<<1) ^ ((row&7)<<4))));
          op[col] = xo + (mv[tn]-mean)*rstd*w2v[tn] + b2n[tn];
        }
      }
  }
}

extern "C" void kernel_launch(void* const* d_in, const int* in_sizes, int n_in,
                              void* d_out, int out_size, void* d_ws, size_t ws_size,
                              hipStream_t stream)
{
  const float* x     = (const float*)d_in[0];
  const float* qkvw  = (const float*)d_in[1];
  const float* qkvb  = (const float*)d_in[2];
  const float* projw = (const float*)d_in[3];
  const float* projb = (const float*)d_in[4];
  const float* tsc   = (const float*)d_in[5];
  const float* w1    = (const float*)d_in[6];
  const float* b1    = (const float*)d_in[7];
  const float* w2    = (const float*)d_in[8];
  const float* n1w   = (const float*)d_in[9];
  const float* n1b   = (const float*)d_in[10];
  const float* n2w   = (const float*)d_in[11];
  const float* n2b   = (const float*)d_in[12];
  const float* fc1w  = (const float*)d_in[13];
  const float* fc1b  = (const float*)d_in[14];
  const float* fc2w  = (const float*)d_in[15];
  const float* fc2b  = (const float*)d_in[16];
  float* out = (float*)d_out;

  char* ws = (char*)d_ws;
  const size_t WB = 134217728;  // z fp16 buffer (64*4096*256*2)
  u16* z_h      = (u16*)(ws);
  u16* qkvw_h   = (u16*)(ws + WB);
  u16* projw_h  = (u16*)(ws + WB + 393216);
  u16* fc1_h    = (u16*)(ws + WB + 524288);
  u16* fc2_h    = (u16*)(ws + WB + 1048576);
  float* biastab= (float*)(ws + WB + 1572864);

  (void)hipFuncSetAttribute((const void*)k_attn,
                      hipFuncAttributeMaxDynamicSharedMemorySize, 135168);

  k_wconv<<<384, 256, 0, stream>>>(qkvw, projw, fc1w, fc2w,
                                   qkvw_h, projw_h, fc1_h, fc2_h);
  k_bias<<<1, 256, 0, stream>>>(w1, b1, w2, biastab);
  k_attn<<<4096, 512, 135168, stream>>>(x, qkvw_h, qkvb, projw_h, projb,
                                        tsc, biastab, n1w, n1b, z_h);
  k_mlp<<<8192, 256, 0, stream>>>(x, z_h, fc1_h, fc1b,
                                  fc2_h, fc2b, n2w, n2b, out);
}